// Round 1
// baseline (1412.463 us; speedup 1.0000x reference)
//
#include <hip/hip_runtime.h>
#include <math.h>

// Problem constants
#define B_  16
#define L_  128
#define E_  34
#define A_  36
#define D_  300
#define H_  256
#define DP_ 304     // D padded to mult of 16
#define G4_ 1024    // 4*H
#define KC_ 512     // 2*H
#define NCAT_ 128   // padded 36(base)+36(trig)+34(evh)
#define WAS_ 1092   // Wa row stride = 4H + A-1 + E-1
#define WES_ 545    // We row stride = 2H + E-1

// Workspace layout (float offsets)
#define O_X      0u         // [2048][304] gathered embeddings (t*16+b rows)
#define O_WIHT_F 622592u    // [304][1024]
#define O_WIHT_B 933888u
#define O_WT4_F  1245184u   // [64][1024][4]  Whh re-tiled: Wt4[k4][r][c] = Whh[r][4*k4+c]
#define O_WT4_B  1507328u
#define O_BSUM_F 1769472u   // [1024] bih+bhh
#define O_BSUM_B 1770496u
#define O_ZPRE   1771520u   // [2][128][16][1024]  x@WihT + bias, in processing order
#define O_HIDDEN 5965824u   // [128][16][512]  hs-layout (t,b), fwd in [0:256), bwd in [256:512)
#define O_WCAT   7014400u   // [512][128]  cols: 0..35 Wa_hidden, 36..71 Wa_trig, 72..105 We_hidden
#define O_BVEC   7079936u   // [128]       ba | 0 | be
#define O_P      7080064u   // [2048][128] hidden @ Wcat + bvec   (rows m = t*16+b)
#define O_EVPRED 7342208u   // [128][16] int

// ---------------------------------------------------------------- prep
__global__ void k_gather(const int* __restrict__ ids, const float* __restrict__ emb,
                         float* __restrict__ ws) {
    int m = blockIdx.x;            // t*16 + b
    int t = m >> 4, b = m & 15;
    int d = threadIdx.x;
    if (d >= DP_) return;
    int id = ids[b * L_ + t];
    float v = (d < D_) ? emb[(size_t)id * D_ + d] : 0.0f;
    ws[O_X + (size_t)m * DP_ + d] = v;
}

__global__ void k_prep(const float* __restrict__ Wih_f, const float* __restrict__ Whh_f,
                       const float* __restrict__ bih_f, const float* __restrict__ bhh_f,
                       const float* __restrict__ Wih_b, const float* __restrict__ Whh_b,
                       const float* __restrict__ bih_b, const float* __restrict__ bhh_b,
                       const float* __restrict__ We, const float* __restrict__ be,
                       const float* __restrict__ Wa, const float* __restrict__ ba,
                       float* __restrict__ ws) {
    const int N1 = 2 * 311296;   // WihT
    const int N2 = 2 * 262144;   // Wt4
    const int N3 = 2 * 1024;     // bsum
    const int N4 = 65536;        // Wcat
    const int N5 = 128;          // bvec
    const int total = N1 + N2 + N3 + N4 + N5;
    for (int idx = blockIdx.x * blockDim.x + threadIdx.x; idx < total;
         idx += gridDim.x * blockDim.x) {
        int i = idx;
        if (i < N1) {
            int dir = i / 311296, rem = i % 311296;
            int k = rem >> 10, r = rem & 1023;
            const float* Wih = dir ? Wih_b : Wih_f;
            ws[(dir ? O_WIHT_B : O_WIHT_F) + rem] = (k < D_) ? Wih[r * D_ + k] : 0.0f;
            continue;
        }
        i -= N1;
        if (i < N2) {
            int dir = i / 262144, rem = i % 262144;
            int c = rem & 3, r = (rem >> 2) & 1023, k4 = rem >> 12;
            const float* Whh = dir ? Whh_b : Whh_f;
            ws[(dir ? O_WT4_B : O_WT4_F) + rem] = Whh[r * H_ + k4 * 4 + c];
            continue;
        }
        i -= N2;
        if (i < N3) {
            int dir = i / 1024, r = i % 1024;
            ws[(dir ? O_BSUM_B : O_BSUM_F) + r] =
                (dir ? bih_b[r] + bhh_b[r] : bih_f[r] + bhh_f[r]);
            continue;
        }
        i -= N3;
        if (i < N4) {
            int k = i >> 7, n = i & 127;
            float v = 0.0f;
            if (n < 36)               v = Wa[n * WAS_ + k];             // hidden part
            else if (n < 72)          v = Wa[(n - 36) * WAS_ + KC_ + k];// trig part
            else if (n < 106)         v = We[(n - 72) * WES_ + k];      // ev hidden part
            ws[O_WCAT + i] = v;
            continue;
        }
        i -= N4;
        {
            float v = 0.0f;
            if (i < 36)               v = ba[i];
            else if (i >= 72 && i < 106) v = be[i - 72];
            ws[O_BVEC + i] = v;
        }
    }
}

// ------------------------------------------------- GEMM1: z_pre = x @ WihT + bsum
// A: x rows (remapped for bwd), K=304(padded), B: WihT[304][1024], C: zpre[2][2048][1024]
__global__ __launch_bounds__(256) void k_gemm1(float* __restrict__ ws) {
    __shared__ float As[16][64];
    __shared__ float Bs[16][64];
    int dir = blockIdx.z;
    int m0 = blockIdx.y * 64;
    int n0 = blockIdx.x * 64;
    int tid = threadIdx.x;
    const float* xp = ws + O_X;
    const float* Bt = ws + (dir ? O_WIHT_B : O_WIHT_F);
    const float* bs = ws + (dir ? O_BSUM_B : O_BSUM_F);
    float acc[4][4] = {};
    int a_m = tid >> 2, a_k = (tid & 3) << 2;
    int b_k = tid >> 4, b_n = (tid & 15) << 2;
    int ty = tid >> 4, tx = tid & 15;
    int mrow = m0 + a_m;
    int t = mrow >> 4, bb = mrow & 15;
    int srow = dir ? (((L_ - 1 - t) << 4) | bb) : mrow;
    const float* arow = xp + (size_t)srow * DP_;
    for (int k0 = 0; k0 < DP_; k0 += 16) {
        float4 av = *(const float4*)(arow + k0 + a_k);
        float4 bv = *(const float4*)(Bt + (size_t)(k0 + b_k) * G4_ + n0 + b_n);
        As[a_k + 0][a_m] = av.x; As[a_k + 1][a_m] = av.y;
        As[a_k + 2][a_m] = av.z; As[a_k + 3][a_m] = av.w;
        *(float4*)&Bs[b_k][b_n] = bv;
        __syncthreads();
#pragma unroll
        for (int kk = 0; kk < 16; kk++) {
            float4 a4 = *(const float4*)&As[kk][ty * 4];
            float4 b4 = *(const float4*)&Bs[kk][tx * 4];
            acc[0][0] = fmaf(a4.x, b4.x, acc[0][0]); acc[0][1] = fmaf(a4.x, b4.y, acc[0][1]);
            acc[0][2] = fmaf(a4.x, b4.z, acc[0][2]); acc[0][3] = fmaf(a4.x, b4.w, acc[0][3]);
            acc[1][0] = fmaf(a4.y, b4.x, acc[1][0]); acc[1][1] = fmaf(a4.y, b4.y, acc[1][1]);
            acc[1][2] = fmaf(a4.y, b4.z, acc[1][2]); acc[1][3] = fmaf(a4.y, b4.w, acc[1][3]);
            acc[2][0] = fmaf(a4.z, b4.x, acc[2][0]); acc[2][1] = fmaf(a4.z, b4.y, acc[2][1]);
            acc[2][2] = fmaf(a4.z, b4.z, acc[2][2]); acc[2][3] = fmaf(a4.z, b4.w, acc[2][3]);
            acc[3][0] = fmaf(a4.w, b4.x, acc[3][0]); acc[3][1] = fmaf(a4.w, b4.y, acc[3][1]);
            acc[3][2] = fmaf(a4.w, b4.z, acc[3][2]); acc[3][3] = fmaf(a4.w, b4.w, acc[3][3]);
        }
        __syncthreads();
    }
    float4 bias = *(const float4*)(bs + n0 + tx * 4);
    float* zp = ws + O_ZPRE + ((size_t)dir * 2048 + m0) * G4_;
#pragma unroll
    for (int i = 0; i < 4; i++) {
        float4 o;
        o.x = acc[i][0] + bias.x; o.y = acc[i][1] + bias.y;
        o.z = acc[i][2] + bias.z; o.w = acc[i][3] + bias.w;
        *(float4*)(zp + (size_t)(ty * 4 + i) * G4_ + n0 + tx * 4) = o;
    }
}

// ------------------------------------------------- LSTM recurrence: 32 blocks = (dir, b)
__global__ __launch_bounds__(1024) void k_lstm(float* __restrict__ ws) {
    int blk = blockIdx.x;
    int dir = blk >> 4, b = blk & 15;
    int r = threadIdx.x;   // 0..1023 output row
    __shared__ float hbuf[256];
    __shared__ float zbuf[1024];
    const float4* Wv = (const float4*)(ws + (dir ? O_WT4_B : O_WT4_F)); // [64*1024] float4
    const float* zpre = ws + O_ZPRE + (size_t)dir * 2048 * G4_;
    float* hid = ws + O_HIDDEN;
    float c = 0.0f;
    if (r < 256) hbuf[r] = 0.0f;
    __syncthreads();
    const float4* h4 = (const float4*)hbuf;
    for (int s = 0; s < L_; s++) {
        float acc = zpre[(size_t)(s * B_ + b) * G4_ + r];
#pragma unroll 8
        for (int k4 = 0; k4 < 64; k4++) {
            float4 w = Wv[(k4 << 10) + r];
            float4 hv = h4[k4];
            acc = fmaf(w.x, hv.x, acc);
            acc = fmaf(w.y, hv.y, acc);
            acc = fmaf(w.z, hv.z, acc);
            acc = fmaf(w.w, hv.w, acc);
        }
        zbuf[r] = acc;
        __syncthreads();
        if (r < 256) {
            float zi = zbuf[r], zf = zbuf[r + 256], zg = zbuf[r + 512], zo = zbuf[r + 768];
            float fi = 1.0f / (1.0f + expf(-zi));
            float ff = 1.0f / (1.0f + expf(-zf));
            float gg = tanhf(zg);
            float fo = 1.0f / (1.0f + expf(-zo));
            c = ff * c + fi * gg;
            float h = fo * tanhf(c);
            hbuf[r] = h;
            int t_orig = dir ? (L_ - 1 - s) : s;
            hid[(size_t)(t_orig * B_ + b) * KC_ + dir * H_ + r] = h;
        }
        __syncthreads();
    }
}

// ------------------------------------------------- GEMM2: P = hidden @ Wcat + bvec
__global__ __launch_bounds__(256) void k_gemm2(float* __restrict__ ws) {
    __shared__ float As[16][64];
    __shared__ float Bs[16][64];
    int m0 = blockIdx.y * 64;
    int n0 = blockIdx.x * 64;
    int tid = threadIdx.x;
    const float* Ap = ws + O_HIDDEN;
    const float* Bp = ws + O_WCAT;
    const float* bv = ws + O_BVEC;
    float acc[4][4] = {};
    int a_m = tid >> 2, a_k = (tid & 3) << 2;
    int b_k = tid >> 4, b_n = (tid & 15) << 2;
    int ty = tid >> 4, tx = tid & 15;
    const float* arow = Ap + (size_t)(m0 + a_m) * KC_;
    for (int k0 = 0; k0 < KC_; k0 += 16) {
        float4 av = *(const float4*)(arow + k0 + a_k);
        float4 bvv = *(const float4*)(Bp + (size_t)(k0 + b_k) * NCAT_ + n0 + b_n);
        As[a_k + 0][a_m] = av.x; As[a_k + 1][a_m] = av.y;
        As[a_k + 2][a_m] = av.z; As[a_k + 3][a_m] = av.w;
        *(float4*)&Bs[b_k][b_n] = bvv;
        __syncthreads();
#pragma unroll
        for (int kk = 0; kk < 16; kk++) {
            float4 a4 = *(const float4*)&As[kk][ty * 4];
            float4 b4 = *(const float4*)&Bs[kk][tx * 4];
            acc[0][0] = fmaf(a4.x, b4.x, acc[0][0]); acc[0][1] = fmaf(a4.x, b4.y, acc[0][1]);
            acc[0][2] = fmaf(a4.x, b4.z, acc[0][2]); acc[0][3] = fmaf(a4.x, b4.w, acc[0][3]);
            acc[1][0] = fmaf(a4.y, b4.x, acc[1][0]); acc[1][1] = fmaf(a4.y, b4.y, acc[1][1]);
            acc[1][2] = fmaf(a4.y, b4.z, acc[1][2]); acc[1][3] = fmaf(a4.y, b4.w, acc[1][3]);
            acc[2][0] = fmaf(a4.z, b4.x, acc[2][0]); acc[2][1] = fmaf(a4.z, b4.y, acc[2][1]);
            acc[2][2] = fmaf(a4.z, b4.z, acc[2][2]); acc[2][3] = fmaf(a4.z, b4.w, acc[2][3]);
            acc[3][0] = fmaf(a4.w, b4.x, acc[3][0]); acc[3][1] = fmaf(a4.w, b4.y, acc[3][1]);
            acc[3][2] = fmaf(a4.w, b4.z, acc[3][2]); acc[3][3] = fmaf(a4.w, b4.w, acc[3][3]);
        }
        __syncthreads();
    }
    float4 bias = *(const float4*)(bv + n0 + tx * 4);
    float* Pp = ws + O_P + (size_t)m0 * NCAT_;
#pragma unroll
    for (int i = 0; i < 4; i++) {
        float4 o;
        o.x = acc[i][0] + bias.x; o.y = acc[i][1] + bias.y;
        o.z = acc[i][2] + bias.z; o.w = acc[i][3] + bias.w;
        *(float4*)(Pp + (size_t)(ty * 4 + i) * NCAT_ + n0 + tx * 4) = o;
    }
}

// ------------------------------------------------- event chain: 16 waves, one per batch
__global__ __launch_bounds__(1024) void k_ev(const float* __restrict__ We,
                                             float* __restrict__ ws, float* __restrict__ out) {
    int b = threadIdx.x >> 6;
    int lane = threadIdx.x & 63;
    const float* P = ws + O_P;
    int* evp = (int*)(ws + O_EVPRED);
    float Cg = 0.0f;
    unsigned long long gmask = 0ull;
    float pv = (lane < E_) ? P[(size_t)(0 * B_ + b) * NCAT_ + 72 + lane] : 0.0f;
    for (int i = 0; i < L_; i++) {
        float pnext = 0.0f;
        if (i + 1 < L_ && lane < E_) pnext = P[(size_t)((i + 1) * B_ + b) * NCAT_ + 72 + lane];
        float v = (lane < E_) ? (pv + Cg) : -INFINITY;
        float mv = v;
        int mi = (lane < E_) ? lane : 0x7fffffff;
#pragma unroll
        for (int off = 32; off; off >>= 1) {
            float ov = __shfl_down(mv, off);
            int oi = __shfl_down(mi, off);
            if (ov > mv || (ov == mv && oi < mi)) { mv = ov; mi = oi; }
        }
        int p = __shfl(mi, 0);
        if (lane < E_) out[(size_t)(b * L_ + i) * E_ + lane] = v;
        if (lane == 0) evp[i * B_ + b] = p;
        if (p > 0) {
            unsigned long long bit = 1ull << (p - 1);
            if (!(gmask & bit)) {
                gmask |= bit;
                if (lane < E_) Cg += We[lane * WES_ + 2 * H_ + (p - 1)];
            }
        }
        pv = pnext;
    }
}

// ------------------------------------------------- argument chains: one wave per (b, j)
__global__ __launch_bounds__(256) void k_arg(const float* __restrict__ Wa,
                                             float* __restrict__ ws, float* __restrict__ out) {
    int w = (blockIdx.x << 2) + (threadIdx.x >> 6);  // 0..2047
    int lane = threadIdx.x & 63;
    int b = w >> 7, j = w & 127;
    const float* P = ws + O_P;
    const int* evp = (const int*)(ws + O_EVPRED);
    float* outa = out + (size_t)B_ * L_ * E_;
    float C = 0.0f;
    if (lane < A_) C = P[(size_t)(j * B_ + b) * NCAT_ + lane];  // base + ba
    unsigned long long ga = 0ull, gta = 0ull;
    float tv = (lane < A_) ? P[(size_t)(0 * B_ + b) * NCAT_ + 36 + lane] : 0.0f;
    for (int i = 0; i < L_; i++) {
        float tnext = 0.0f;
        if (i + 1 < L_ && lane < A_) tnext = P[(size_t)((i + 1) * B_ + b) * NCAT_ + 36 + lane];
        int ev = evp[i * B_ + b];
        float v = (lane < A_) ? (C + tv) : -INFINITY;
        float mv = v;
        int mi = (lane < A_) ? lane : 0x7fffffff;
#pragma unroll
        for (int off = 32; off; off >>= 1) {
            float ov = __shfl_down(mv, off);
            int oi = __shfl_down(mi, off);
            if (ov > mv || (ov == mv && oi < mi)) { mv = ov; mi = oi; }
        }
        int p = __shfl(mi, 0);
        if (lane < A_) outa[(size_t)((b * L_ + i) * L_ + j) * A_ + lane] = v;
        if (ev > 0 && p > 0) {
            unsigned long long bq = 1ull << (ev - 1);
            if (!(gta & bq)) {
                gta |= bq;
                if (lane < A_) C += Wa[lane * WAS_ + 4 * H_ + A_ - 1 + (ev - 1)];
            }
            unsigned long long br = 1ull << (p - 1);
            if (!(ga & br)) {
                ga |= br;
                if (lane < A_) C += Wa[lane * WAS_ + 4 * H_ + (p - 1)];
            }
        }
        tv = tnext;
    }
}

// ----------------------------------------------------------------
extern "C" void kernel_launch(void* const* d_in, const int* in_sizes, int n_in,
                              void* d_out, int out_size, void* d_ws, size_t ws_size,
                              hipStream_t stream) {
    (void)in_sizes; (void)n_in; (void)out_size; (void)ws_size;
    const int*   ids   = (const int*)d_in[0];
    const float* emb   = (const float*)d_in[1];
    const float* Wih_f = (const float*)d_in[2];
    const float* Whh_f = (const float*)d_in[3];
    const float* bih_f = (const float*)d_in[4];
    const float* bhh_f = (const float*)d_in[5];
    const float* Wih_b = (const float*)d_in[6];
    const float* Whh_b = (const float*)d_in[7];
    const float* bih_b = (const float*)d_in[8];
    const float* bhh_b = (const float*)d_in[9];
    const float* We    = (const float*)d_in[10];
    const float* be    = (const float*)d_in[11];
    const float* Wa    = (const float*)d_in[12];
    const float* ba    = (const float*)d_in[13];
    float* out = (float*)d_out;
    float* ws  = (float*)d_ws;

    hipLaunchKernelGGL(k_gather, dim3(2048), dim3(320), 0, stream, ids, emb, ws);
    hipLaunchKernelGGL(k_prep, dim3(2048), dim3(256), 0, stream,
                       Wih_f, Whh_f, bih_f, bhh_f, Wih_b, Whh_b, bih_b, bhh_b,
                       We, be, Wa, ba, ws);
    hipLaunchKernelGGL(k_gemm1, dim3(16, 32, 2), dim3(256), 0, stream, ws);
    hipLaunchKernelGGL(k_lstm, dim3(32), dim3(1024), 0, stream, ws);
    hipLaunchKernelGGL(k_gemm2, dim3(2, 32, 1), dim3(256), 0, stream, ws);
    hipLaunchKernelGGL(k_ev, dim3(1), dim3(1024), 0, stream, We, ws, out);
    hipLaunchKernelGGL(k_arg, dim3(512), dim3(256), 0, stream, Wa, ws, out);
}